// Round 5
// baseline (256.716 us; speedup 1.0000x reference)
//
#include <hip/hip_runtime.h>
#include <hip/hip_bf16.h>

// SkipGCN: out = gcn(relu(gcn(x,W1,b1)),W2,b2) + x@Ws + bs
// N=100000, E=1600000, in=165, hid=128, out=2, fp32 in/out.
//
// R4 changes vs R3:
//  - CSR build rewritten: count+scan123+fill (5 kernels, ~190us, fill had 16x
//    write amplification: 105MB WRITE for 6.4MB payload) replaced by
//    partition->bscan->buildB. Scatters confined to block-local bucket
//    regions so L2 lines go fully dirty before eviction.
//  - deg/dinv/row_ptr now derived from bucket records (count_kernel deleted).
//  - gemm1 (MFMA), agg1, agg2 unchanged from R3.

#define IND 165
#define HID 128
#define KP 192          // padded K for MFMA
#define XSS 200         // LDS row stride in bf16 elems
#define SLAB 8192       // per-bucket slab capacity (avg fill ~4092, 64 sigma)
#define MAXNB 512       // max buckets (supports n up to 131072)

typedef __attribute__((ext_vector_type(8))) short short8v;
typedef __attribute__((ext_vector_type(4))) float float4v;

__device__ __forceinline__ unsigned short f2bf(float f) {
    unsigned u = __float_as_uint(f);
    unsigned r = (u + 0x7FFF + ((u >> 16) & 1)) >> 16;  // RNE
    return (unsigned short)r;
}
__device__ __forceinline__ float bf_lo(unsigned u) { return __uint_as_float(u << 16); }
__device__ __forceinline__ float bf_hi(unsigned u) { return __uint_as_float(u & 0xFFFF0000u); }

__global__ void detect_kernel(const int* e32, int* flag) {
    __shared__ int nz;
    if (threadIdx.x == 0) nz = 0;
    __syncthreads();
    if (e32[2 * threadIdx.x + 1] != 0) atomicOr(&nz, 1);
    __syncthreads();
    if (threadIdx.x == 0) flag[0] = (nz == 0) ? 1 : 0;  // 1 => int64 layout
}

// ---- partition: edges -> per-bucket slabs of records (dstLow<<24 | src) ----
// 8192 edges/block, 32/thread (fully unrolled -> registers, rule #20).
__global__ __launch_bounds__(256) void partition_kernel(const int* __restrict__ e32,
                                                        const int* __restrict__ flag,
                                                        int* __restrict__ bucket_len,
                                                        unsigned* __restrict__ slab,
                                                        int E, int NB) {
    __shared__ unsigned hist[MAXNB];
    __shared__ unsigned runbase[MAXNB];
    __shared__ unsigned cnt2[MAXNB];
    for (int t = threadIdx.x; t < NB; t += 256) { hist[t] = 0; cnt2[t] = 0; }
    __syncthreads();
    const int f = flag[0];
    const int base = blockIdx.x * 8192;
    unsigned rec[32];
    unsigned bk[32];
    #pragma unroll
    for (int j = 0; j < 32; ++j) {
        int e = base + j * 256 + threadIdx.x;
        if (e < E) {
            int src, dst;
            if (f) {
                int2 s2 = ((const int2*)e32)[e];
                int2 d2 = ((const int2*)e32)[E + e];
                src = s2.x; dst = d2.x;
            } else {
                src = e32[e];
                dst = e32[E + e];
            }
            unsigned b = (unsigned)dst >> 8;
            rec[j] = ((unsigned)(dst & 255) << 24) | (unsigned)src;
            bk[j] = b;
            atomicAdd(&hist[b], 1u);
        } else {
            bk[j] = 0xFFFFFFFFu;
            rec[j] = 0;
        }
    }
    __syncthreads();
    for (int t = threadIdx.x; t < NB; t += 256) {
        unsigned h = hist[t];
        runbase[t] = h ? (unsigned)atomicAdd(&bucket_len[t], (int)h) : 0u;
    }
    __syncthreads();
    #pragma unroll
    for (int j = 0; j < 32; ++j) {
        unsigned b = bk[j];
        if (b != 0xFFFFFFFFu) {
            unsigned p = runbase[b] + atomicAdd(&cnt2[b], 1u);
            if (p < SLAB) slab[(size_t)b * SLAB + p] = rec[j];
        }
    }
}

// ---- bscan: exclusive scan of bucket lengths -> bucket_base[NB+1], row_ptr[n] ----
__global__ __launch_bounds__(256) void bscan_kernel(const int* __restrict__ bucket_len,
                                                    int* __restrict__ bucket_base,
                                                    int* __restrict__ row_ptr, int n, int NB) {
    __shared__ int sa[MAXNB], sb[MAXNB];
    int t = threadIdx.x;
    for (int i = t; i < MAXNB; i += 256) sa[i] = (i < NB) ? min(bucket_len[i], SLAB) : 0;
    __syncthreads();
    int* s = sa; int* d = sb;
    for (int off = 1; off < MAXNB; off <<= 1) {
        for (int i = t; i < MAXNB; i += 256) d[i] = s[i] + ((i >= off) ? s[i - off] : 0);
        __syncthreads();
        int* tmp = s; s = d; d = tmp;
    }
    // s = inclusive scan
    for (int i = t; i <= NB; i += 256) bucket_base[i] = (i == 0) ? 0 : s[i - 1];
    if (t == 0) row_ptr[n] = s[NB - 1];
}

// ---- buildB: block per bucket -> deg/dinv/row_ptr + col_src scatter ----
__global__ __launch_bounds__(256) void buildb_kernel(const unsigned* __restrict__ slab,
                                                     const int* __restrict__ bucket_len,
                                                     const int* __restrict__ bucket_base,
                                                     int* __restrict__ row_ptr,
                                                     float* __restrict__ dinv,
                                                     int* __restrict__ col_src, int n) {
    __shared__ unsigned deg[256];
    __shared__ unsigned sa[256], sb[256];
    __shared__ unsigned cur[256];
    const int b = blockIdx.x;
    int len = min(bucket_len[b], SLAB);
    const int bb = bucket_base[b];
    const unsigned* recs = slab + (size_t)b * SLAB;
    const int d0 = b << 8;
    const int t = threadIdx.x;
    deg[t] = 0;
    __syncthreads();
    for (int i = t; i < len; i += 256) atomicAdd(&deg[recs[i] >> 24], 1u);
    __syncthreads();
    unsigned dv = deg[t];
    sa[t] = dv;
    __syncthreads();
    unsigned* s = sa; unsigned* d = sb;
    for (int off = 1; off < 256; off <<= 1) {
        d[t] = s[t] + ((t >= off) ? s[t - off] : 0);
        __syncthreads();
        unsigned* tmp = s; s = d; d = tmp;
    }
    unsigned excl = s[t] - dv;
    if (d0 + t < n) {
        dinv[d0 + t] = rsqrtf(1.0f + (float)dv);
        row_ptr[d0 + t] = bb + (int)excl;
    }
    cur[t] = excl;
    __syncthreads();
    for (int i = t; i < len; i += 256) {
        unsigned r = recs[i];
        unsigned p = (unsigned)bb + atomicAdd(&cur[r >> 24], 1u);
        col_src[p] = (int)(r & 0xFFFFFFu);
    }
}

// ---- W1 [165][128] f32 -> W1^T [128][192] bf16 (k-padded) ----
__global__ void w1t_kernel(const float* __restrict__ W1, unsigned short* __restrict__ w1t) {
    int t = blockIdx.x * 256 + threadIdx.x;
    if (t >= HID * KP) return;
    int nn = t / KP, k = t - nn * KP;
    w1t[t] = (k < IND) ? f2bf(W1[k * HID + nn]) : (unsigned short)0;
}

// ---- MFMA gemm1: hb(bf16) = x @ W1, fused skip = x @ Ws + bs + b2 ----
__global__ __launch_bounds__(256) void gemm1_kernel(const float* __restrict__ x,
                                                    const unsigned short* __restrict__ w1t,
                                                    const float* __restrict__ Ws,
                                                    const float* __restrict__ bs,
                                                    const float* __restrict__ b2,
                                                    unsigned short* __restrict__ hb,
                                                    float* __restrict__ skip, int n) {
    __shared__ unsigned short xs[64 * XSS];
    const int row0 = blockIdx.x * 64;

    for (int t = threadIdx.x; t < 64 * 40; t += 256) {
        int r = t / 40, k = 160 + (t - (t / 40) * 40);
        xs[r * XSS + k] = 0;
    }
    for (int t = threadIdx.x; t < 64 * IND; t += 256) {
        int r = t / IND, k = t - r * IND;
        int row = row0 + r;
        float v = (row < n) ? x[(size_t)row * IND + k] : 0.f;
        xs[r * XSS + k] = f2bf(v);
    }
    __syncthreads();

    const int wave = threadIdx.x >> 6, lane = threadIdx.x & 63;
    const int l15 = lane & 15, lk = (lane >> 4) * 8;

    float4v acc[8];
    #pragma unroll
    for (int nt = 0; nt < 8; ++nt) acc[nt] = (float4v){0.f, 0.f, 0.f, 0.f};

    const unsigned short* arow = xs + (wave * 16 + l15) * XSS;
    #pragma unroll
    for (int ks = 0; ks < 6; ++ks) {
        int k0 = ks * 32 + lk;
        short8v a = *(const short8v*)(arow + k0);
        #pragma unroll
        for (int nt = 0; nt < 8; ++nt) {
            short8v b = *(const short8v*)(w1t + (size_t)(nt * 16 + l15) * KP + k0);
            acc[nt] = __builtin_amdgcn_mfma_f32_16x16x32_bf16(a, b, acc[nt], 0, 0, 0);
        }
    }

    const int orow0 = row0 + wave * 16 + (lane >> 4) * 4;
    #pragma unroll
    for (int nt = 0; nt < 8; ++nt) {
        int col = nt * 16 + l15;
        #pragma unroll
        for (int r = 0; r < 4; ++r) {
            int row = orow0 + r;
            if (row < n) hb[(size_t)row * HID + col] = f2bf(acc[nt][r]);
        }
    }

    {
        int r = threadIdx.x >> 2, j = threadIdx.x & 3;
        int row = row0 + r;
        float s0 = 0.f, s1 = 0.f;
        if (row < n) {
            const float* xr = x + (size_t)row * IND;
            const float2* Wsv = (const float2*)Ws;
            for (int k = j; k < IND; k += 4) {
                float xv = xr[k];
                float2 w = Wsv[k];
                s0 = fmaf(xv, w.x, s0);
                s1 = fmaf(xv, w.y, s1);
            }
        }
        s0 += __shfl_xor(s0, 1); s0 += __shfl_xor(s0, 2);
        s1 += __shfl_xor(s1, 1); s1 += __shfl_xor(s1, 2);
        if (j == 0 && row < n)
            ((float2*)skip)[row] = make_float2(s0 + bs[0] + b2[0], s1 + bs[1] + b2[1]);
    }
}

// ---- layer-1 aggregate (bf16 h) + relu + fused h2 = relu(agg+b1) @ W2 ----
__global__ __launch_bounds__(256) void agg1_kernel(const unsigned* __restrict__ hbu,
                                                   const float* __restrict__ dinv,
                                                   const int* __restrict__ row_ptr,
                                                   const int* __restrict__ col_src,
                                                   const float* __restrict__ b1,
                                                   const float* __restrict__ W2,
                                                   float* __restrict__ h2, int n) {
    int wid = threadIdx.x >> 6, lane = threadIdx.x & 63;
    int i = blockIdx.x * 4 + wid;
    if (i >= n) return;
    float di = dinv[i];
    float ax, ay;
    {
        unsigned u = hbu[(size_t)i * 64 + lane];
        float w = di * di;
        ax = bf_lo(u) * w;
        ay = bf_hi(u) * w;
    }
    int e = row_ptr[i], end = row_ptr[i + 1];
    for (; e + 4 <= end; e += 4) {
        int s0 = col_src[e], s1 = col_src[e + 1], s2 = col_src[e + 2], s3 = col_src[e + 3];
        float n0 = dinv[s0] * di, n1 = dinv[s1] * di, n2 = dinv[s2] * di, n3 = dinv[s3] * di;
        unsigned u0 = hbu[(size_t)s0 * 64 + lane];
        unsigned u1 = hbu[(size_t)s1 * 64 + lane];
        unsigned u2 = hbu[(size_t)s2 * 64 + lane];
        unsigned u3 = hbu[(size_t)s3 * 64 + lane];
        ax = fmaf(bf_lo(u0), n0, ax); ay = fmaf(bf_hi(u0), n0, ay);
        ax = fmaf(bf_lo(u1), n1, ax); ay = fmaf(bf_hi(u1), n1, ay);
        ax = fmaf(bf_lo(u2), n2, ax); ay = fmaf(bf_hi(u2), n2, ay);
        ax = fmaf(bf_lo(u3), n3, ax); ay = fmaf(bf_hi(u3), n3, ay);
    }
    for (; e < end; ++e) {
        int s = col_src[e];
        float nrm = dinv[s] * di;
        unsigned u = hbu[(size_t)s * 64 + lane];
        ax = fmaf(bf_lo(u), nrm, ax);
        ay = fmaf(bf_hi(u), nrm, ay);
    }
    float2 bb = ((const float2*)b1)[lane];
    float vx = fmaxf(ax + bb.x, 0.f);
    float vy = fmaxf(ay + bb.y, 0.f);
    float2 w2a = ((const float2*)W2)[2 * lane];
    float2 w2b = ((const float2*)W2)[2 * lane + 1];
    float p0 = vx * w2a.x + vy * w2b.x;
    float p1 = vx * w2a.y + vy * w2b.y;
    #pragma unroll
    for (int off = 32; off; off >>= 1) {
        p0 += __shfl_xor(p0, off);
        p1 += __shfl_xor(p1, off);
    }
    if (lane == 0) ((float2*)h2)[i] = make_float2(p0, p1);
}

// ---- layer-2 aggregate + skip ----
__global__ __launch_bounds__(256) void agg2_kernel(const float* __restrict__ h2,
                                                   const float* __restrict__ dinv,
                                                   const int* __restrict__ row_ptr,
                                                   const int* __restrict__ col_src,
                                                   const float* __restrict__ skip,
                                                   float* __restrict__ out, int n) {
    int i = blockIdx.x * blockDim.x + threadIdx.x;
    if (i >= n) return;
    float di = dinv[i];
    const float2* h2v = (const float2*)h2;
    float2 self = h2v[i];
    float a0 = self.x * di * di, a1 = self.y * di * di;
    int beg = row_ptr[i], end = row_ptr[i + 1];
    for (int e = beg; e < end; ++e) {
        int s = col_src[e];
        float nrm = dinv[s] * di;
        float2 hs = h2v[s];
        a0 = fmaf(hs.x, nrm, a0);
        a1 = fmaf(hs.y, nrm, a1);
    }
    float2 sk = ((const float2*)skip)[i];
    ((float2*)out)[i] = make_float2(a0 + sk.x, a1 + sk.y);
}

extern "C" void kernel_launch(void* const* d_in, const int* in_sizes, int n_in,
                              void* d_out, int out_size, void* d_ws, size_t ws_size,
                              hipStream_t stream) {
    const float* x  = (const float*)d_in[0];
    const int*   ei = (const int*)d_in[1];
    const float* W1 = (const float*)d_in[2];
    const float* b1 = (const float*)d_in[3];
    const float* W2 = (const float*)d_in[4];
    const float* b2 = (const float*)d_in[5];
    const float* Ws = (const float*)d_in[6];
    const float* bs = (const float*)d_in[7];
    float* out = (float*)d_out;

    const int n = in_sizes[0] / IND;        // 100000
    const int E = in_sizes[1] / 2;          // 1600000
    const int NB = (n + 255) >> 8;          // 391 buckets of 256 nodes

    char* ws = (char*)d_ws;
    size_t off = 0;
    auto alloc = [&](size_t bytes) { void* p = ws + off; off += (bytes + 255) & ~(size_t)255; return p; };
    int*            flag        = (int*)alloc(256);
    int*            bucket_len  = (int*)alloc((size_t)(MAXNB + 1) * 4);
    int*            bucket_base = (int*)alloc((size_t)(MAXNB + 1) * 4);
    unsigned*       slab        = (unsigned*)alloc((size_t)NB * SLAB * 4);
    int*            row_ptr     = (int*)alloc((size_t)(n + 1) * 4);
    float*          dinv        = (float*)alloc((size_t)n * 4);
    int*            col_src     = (int*)alloc((size_t)E * 4);
    unsigned short* hb          = (unsigned short*)alloc((size_t)n * HID * 2);
    float*          h2          = (float*)alloc((size_t)n * 2 * 4);
    float*          skip        = (float*)alloc((size_t)n * 2 * 4);
    unsigned short* w1t         = (unsigned short*)alloc((size_t)HID * KP * 2);
    (void)ws_size;

    hipMemsetAsync(bucket_len, 0, (size_t)NB * 4, stream);
    detect_kernel<<<1, 256, 0, stream>>>(ei, flag);
    w1t_kernel<<<(HID * KP + 255) / 256, 256, 0, stream>>>(W1, w1t);
    partition_kernel<<<(E + 8191) / 8192, 256, 0, stream>>>(ei, flag, bucket_len, slab, E, NB);
    bscan_kernel<<<1, 256, 0, stream>>>(bucket_len, bucket_base, row_ptr, n, NB);
    buildb_kernel<<<NB, 256, 0, stream>>>(slab, bucket_len, bucket_base, row_ptr, dinv, col_src, n);

    gemm1_kernel<<<(n + 63) / 64, 256, 0, stream>>>(x, w1t, Ws, bs, b2, hb, skip, n);
    agg1_kernel<<<(n + 3) / 4, 256, 0, stream>>>((const unsigned*)hb, dinv, row_ptr, col_src, b1, W2, h2, n);
    agg2_kernel<<<(n + 255) / 256, 256, 0, stream>>>(h2, dinv, row_ptr, col_src, skip, out, n);
}

// Round 6
// 194.999 us; speedup vs baseline: 1.3165x; 1.3165x over previous
//
#include <hip/hip_runtime.h>
#include <hip/hip_bf16.h>

// SkipGCN: out = gcn(relu(gcn(x,W1,b1)),W2,b2) + x@Ws + bs
// N=100000, E=1600000, in=165, hid=128, out=2, fp32 in/out.
//
// R6 changes vs R5 (gemm1 was 122us, latency-bound: MfmaUtil 1.5%,
// VALUBusy 11%, occ 33%; two per-block latency chains):
//  - BM 64->32: 3125 blocks (12/CU queued) for TLP.
//  - B-fragments (w1t) hoisted to 48 VGPRs, loads issued BEFORE the staging
//    barrier (latency overlaps staging; kills the 48 in-loop L2-load chain).
//  - skip computed from LDS-staged bf16 x (was: 42 global x re-reads per
//    thread as a serial tail -> the ~20us/block killer).
//  - staging via flat float2 copy; LDS stride 208 (16B-aligned rows).
//  - CSR build (partition/bscan/buildb), agg1, agg2 unchanged from R5.

#define IND 165
#define HID 128
#define KP 192          // padded K for MFMA
#define BM 32           // rows per block (gemm1)
#define XSS2 208        // LDS row stride in bf16 (416B = 16B-aligned rows)
#define SLAB 8192
#define MAXNB 512

typedef __attribute__((ext_vector_type(8))) short short8v;
typedef __attribute__((ext_vector_type(4))) float float4v;

__device__ __forceinline__ unsigned short f2bf(float f) {
    unsigned u = __float_as_uint(f);
    unsigned r = (u + 0x7FFF + ((u >> 16) & 1)) >> 16;  // RNE
    return (unsigned short)r;
}
__device__ __forceinline__ float bf_lo(unsigned u) { return __uint_as_float(u << 16); }
__device__ __forceinline__ float bf_hi(unsigned u) { return __uint_as_float(u & 0xFFFF0000u); }
__device__ __forceinline__ float bf2f(unsigned short s) { return __uint_as_float(((unsigned)s) << 16); }

__global__ void detect_kernel(const int* e32, int* flag) {
    __shared__ int nz;
    if (threadIdx.x == 0) nz = 0;
    __syncthreads();
    if (e32[2 * threadIdx.x + 1] != 0) atomicOr(&nz, 1);
    __syncthreads();
    if (threadIdx.x == 0) flag[0] = (nz == 0) ? 1 : 0;  // 1 => int64 layout
}

// ---- partition: edges -> per-bucket slabs of records (dstLow<<24 | src) ----
__global__ __launch_bounds__(256) void partition_kernel(const int* __restrict__ e32,
                                                        const int* __restrict__ flag,
                                                        int* __restrict__ bucket_len,
                                                        unsigned* __restrict__ slab,
                                                        int E, int NB) {
    __shared__ unsigned hist[MAXNB];
    __shared__ unsigned runbase[MAXNB];
    __shared__ unsigned cnt2[MAXNB];
    for (int t = threadIdx.x; t < NB; t += 256) { hist[t] = 0; cnt2[t] = 0; }
    __syncthreads();
    const int f = flag[0];
    const int base = blockIdx.x * 8192;
    unsigned rec[32];
    unsigned bk[32];
    #pragma unroll
    for (int j = 0; j < 32; ++j) {
        int e = base + j * 256 + threadIdx.x;
        if (e < E) {
            int src, dst;
            if (f) {
                int2 s2 = ((const int2*)e32)[e];
                int2 d2 = ((const int2*)e32)[E + e];
                src = s2.x; dst = d2.x;
            } else {
                src = e32[e];
                dst = e32[E + e];
            }
            unsigned b = (unsigned)dst >> 8;
            rec[j] = ((unsigned)(dst & 255) << 24) | (unsigned)src;
            bk[j] = b;
            atomicAdd(&hist[b], 1u);
        } else {
            bk[j] = 0xFFFFFFFFu;
            rec[j] = 0;
        }
    }
    __syncthreads();
    for (int t = threadIdx.x; t < NB; t += 256) {
        unsigned h = hist[t];
        runbase[t] = h ? (unsigned)atomicAdd(&bucket_len[t], (int)h) : 0u;
    }
    __syncthreads();
    #pragma unroll
    for (int j = 0; j < 32; ++j) {
        unsigned b = bk[j];
        if (b != 0xFFFFFFFFu) {
            unsigned p = runbase[b] + atomicAdd(&cnt2[b], 1u);
            if (p < SLAB) slab[(size_t)b * SLAB + p] = rec[j];
        }
    }
}

// ---- bscan: exclusive scan of bucket lengths ----
__global__ __launch_bounds__(256) void bscan_kernel(const int* __restrict__ bucket_len,
                                                    int* __restrict__ bucket_base,
                                                    int* __restrict__ row_ptr, int n, int NB) {
    __shared__ int sa[MAXNB], sb[MAXNB];
    int t = threadIdx.x;
    for (int i = t; i < MAXNB; i += 256) sa[i] = (i < NB) ? min(bucket_len[i], SLAB) : 0;
    __syncthreads();
    int* s = sa; int* d = sb;
    for (int off = 1; off < MAXNB; off <<= 1) {
        for (int i = t; i < MAXNB; i += 256) d[i] = s[i] + ((i >= off) ? s[i - off] : 0);
        __syncthreads();
        int* tmp = s; s = d; d = tmp;
    }
    for (int i = t; i <= NB; i += 256) bucket_base[i] = (i == 0) ? 0 : s[i - 1];
    if (t == 0) row_ptr[n] = s[NB - 1];
}

// ---- buildB: block per bucket -> deg/dinv/row_ptr + col_src scatter ----
__global__ __launch_bounds__(256) void buildb_kernel(const unsigned* __restrict__ slab,
                                                     const int* __restrict__ bucket_len,
                                                     const int* __restrict__ bucket_base,
                                                     int* __restrict__ row_ptr,
                                                     float* __restrict__ dinv,
                                                     int* __restrict__ col_src, int n) {
    __shared__ unsigned deg[256];
    __shared__ unsigned sa[256], sb[256];
    __shared__ unsigned cur[256];
    const int b = blockIdx.x;
    int len = min(bucket_len[b], SLAB);
    const int bb = bucket_base[b];
    const unsigned* recs = slab + (size_t)b * SLAB;
    const int d0 = b << 8;
    const int t = threadIdx.x;
    deg[t] = 0;
    __syncthreads();
    for (int i = t; i < len; i += 256) atomicAdd(&deg[recs[i] >> 24], 1u);
    __syncthreads();
    unsigned dv = deg[t];
    sa[t] = dv;
    __syncthreads();
    unsigned* s = sa; unsigned* d = sb;
    for (int off = 1; off < 256; off <<= 1) {
        d[t] = s[t] + ((t >= off) ? s[t - off] : 0);
        __syncthreads();
        unsigned* tmp = s; s = d; d = tmp;
    }
    unsigned excl = s[t] - dv;
    if (d0 + t < n) {
        dinv[d0 + t] = rsqrtf(1.0f + (float)dv);
        row_ptr[d0 + t] = bb + (int)excl;
    }
    cur[t] = excl;
    __syncthreads();
    for (int i = t; i < len; i += 256) {
        unsigned r = recs[i];
        unsigned p = (unsigned)bb + atomicAdd(&cur[r >> 24], 1u);
        col_src[p] = (int)(r & 0xFFFFFFu);
    }
}

// ---- W1 [165][128] f32 -> W1^T [128][192] bf16 (k-padded) ----
__global__ void w1t_kernel(const float* __restrict__ W1, unsigned short* __restrict__ w1t) {
    int t = blockIdx.x * 256 + threadIdx.x;
    if (t >= HID * KP) return;
    int nn = t / KP, k = t - nn * KP;
    w1t[t] = (k < IND) ? f2bf(W1[k * HID + nn]) : (unsigned short)0;
}

// ---- MFMA gemm1: hb(bf16) = x @ W1, fused skip = x @ Ws + bs + b2 ----
// BM=32 rows x 128 cols per block, 4 waves; wave w owns cols [32w,32w+32).
__global__ __launch_bounds__(256, 4) void gemm1_kernel(const float* __restrict__ x,
                                                       const unsigned short* __restrict__ w1t,
                                                       const float* __restrict__ Ws,
                                                       const float* __restrict__ bs,
                                                       const float* __restrict__ b2,
                                                       unsigned short* __restrict__ hb,
                                                       float* __restrict__ skip, int n) {
    __shared__ unsigned short xs[BM * XSS2];
    const int row0 = blockIdx.x * BM;
    const int tid = threadIdx.x;
    const int wave = tid >> 6, lane = tid & 63;
    const int l15 = lane & 15, lk = (lane >> 4) * 8;

    // hoist B fragments: wave needs cols [32w,32w+32) -> w1t rows, 12 x 16B.
    // Issued before staging so global latency overlaps the x copy.
    short8v bfr[12];
    #pragma unroll
    for (int nt2 = 0; nt2 < 2; ++nt2)
        #pragma unroll
        for (int ks = 0; ks < 6; ++ks)
            bfr[nt2 * 6 + ks] =
                *(const short8v*)(w1t + (size_t)((2 * wave + nt2) * 16 + l15) * KP + ks * 32 + lk);

    // zero-pad k in [165,208)
    for (int t = tid; t < BM * (XSS2 - IND); t += 256) {
        int r = t / (XSS2 - IND), k = IND + (t - r * (XSS2 - IND));
        xs[r * XSS2 + k] = 0;
    }
    // stage x rows bf16 via flat float2 copy (block base is 8B-aligned)
    {
        const int rows = min(BM, n - row0);
        const int nflt = rows * IND;
        const float2* xsrc = (const float2*)(x + (size_t)row0 * IND);
        const int nf2 = nflt >> 1;
        for (int f = tid; f < nf2; f += 256) {
            float2 v = xsrc[f];
            int e0 = 2 * f;
            int r0 = e0 / IND, k0 = e0 - r0 * IND;
            xs[r0 * XSS2 + k0] = f2bf(v.x);
            int r1 = (k0 == IND - 1) ? r0 + 1 : r0;
            int k1 = (k0 == IND - 1) ? 0 : k0 + 1;
            xs[r1 * XSS2 + k1] = f2bf(v.y);
        }
        if ((nflt & 1) && tid == 0) {
            int e = nflt - 1;
            int r = e / IND, k = e - r * IND;
            xs[r * XSS2 + k] = f2bf(x[(size_t)row0 * IND + e]);
        }
    }
    __syncthreads();

    // MFMA: 2 m-tiles x 2 n-tiles x 6 k-steps
    float4v acc[2][2];
    #pragma unroll
    for (int m = 0; m < 2; ++m)
        #pragma unroll
        for (int nt2 = 0; nt2 < 2; ++nt2) acc[m][nt2] = (float4v){0.f, 0.f, 0.f, 0.f};
    #pragma unroll
    for (int m = 0; m < 2; ++m) {
        const unsigned short* arow = xs + (m * 16 + l15) * XSS2;
        #pragma unroll
        for (int ks = 0; ks < 6; ++ks) {
            short8v a = *(const short8v*)(arow + ks * 32 + lk);
            acc[m][0] = __builtin_amdgcn_mfma_f32_16x16x32_bf16(a, bfr[ks], acc[m][0], 0, 0, 0);
            acc[m][1] = __builtin_amdgcn_mfma_f32_16x16x32_bf16(a, bfr[6 + ks], acc[m][1], 0, 0, 0);
        }
    }

    // epilogue: C layout col=lane&15, row=(lane>>4)*4+r
    #pragma unroll
    for (int m = 0; m < 2; ++m) {
        int orow0 = row0 + m * 16 + (lane >> 4) * 4;
        #pragma unroll
        for (int nt2 = 0; nt2 < 2; ++nt2) {
            int col = (2 * wave + nt2) * 16 + l15;
            #pragma unroll
            for (int r = 0; r < 4; ++r) {
                int row = orow0 + r;
                if (row < n) hb[(size_t)row * HID + col] = f2bf(acc[m][nt2][r]);
            }
        }
    }

    // skip from LDS bf16: 8 threads per row
    {
        int r = tid >> 3, j = tid & 7;
        int row = row0 + r;
        float s0 = 0.f, s1 = 0.f;
        if (row < n) {
            const float2* Wsv = (const float2*)Ws;
            const unsigned short* xr = xs + r * XSS2;
            for (int k = j; k < IND; k += 8) {
                float xv = bf2f(xr[k]);
                float2 w = Wsv[k];
                s0 = fmaf(xv, w.x, s0);
                s1 = fmaf(xv, w.y, s1);
            }
        }
        s0 += __shfl_xor(s0, 1); s0 += __shfl_xor(s0, 2); s0 += __shfl_xor(s0, 4);
        s1 += __shfl_xor(s1, 1); s1 += __shfl_xor(s1, 2); s1 += __shfl_xor(s1, 4);
        if (j == 0 && row < n)
            ((float2*)skip)[row] = make_float2(s0 + bs[0] + b2[0], s1 + bs[1] + b2[1]);
    }
}

// ---- layer-1 aggregate (bf16 h) + relu + fused h2 = relu(agg+b1) @ W2 ----
__global__ __launch_bounds__(256) void agg1_kernel(const unsigned* __restrict__ hbu,
                                                   const float* __restrict__ dinv,
                                                   const int* __restrict__ row_ptr,
                                                   const int* __restrict__ col_src,
                                                   const float* __restrict__ b1,
                                                   const float* __restrict__ W2,
                                                   float* __restrict__ h2, int n) {
    int wid = threadIdx.x >> 6, lane = threadIdx.x & 63;
    int i = blockIdx.x * 4 + wid;
    if (i >= n) return;
    float di = dinv[i];
    float ax, ay;
    {
        unsigned u = hbu[(size_t)i * 64 + lane];
        float w = di * di;
        ax = bf_lo(u) * w;
        ay = bf_hi(u) * w;
    }
    int e = row_ptr[i], end = row_ptr[i + 1];
    for (; e + 4 <= end; e += 4) {
        int s0 = col_src[e], s1 = col_src[e + 1], s2 = col_src[e + 2], s3 = col_src[e + 3];
        float n0 = dinv[s0] * di, n1 = dinv[s1] * di, n2 = dinv[s2] * di, n3 = dinv[s3] * di;
        unsigned u0 = hbu[(size_t)s0 * 64 + lane];
        unsigned u1 = hbu[(size_t)s1 * 64 + lane];
        unsigned u2 = hbu[(size_t)s2 * 64 + lane];
        unsigned u3 = hbu[(size_t)s3 * 64 + lane];
        ax = fmaf(bf_lo(u0), n0, ax); ay = fmaf(bf_hi(u0), n0, ay);
        ax = fmaf(bf_lo(u1), n1, ax); ay = fmaf(bf_hi(u1), n1, ay);
        ax = fmaf(bf_lo(u2), n2, ax); ay = fmaf(bf_hi(u2), n2, ay);
        ax = fmaf(bf_lo(u3), n3, ax); ay = fmaf(bf_hi(u3), n3, ay);
    }
    for (; e < end; ++e) {
        int s = col_src[e];
        float nrm = dinv[s] * di;
        unsigned u = hbu[(size_t)s * 64 + lane];
        ax = fmaf(bf_lo(u), nrm, ax);
        ay = fmaf(bf_hi(u), nrm, ay);
    }
    float2 bb = ((const float2*)b1)[lane];
    float vx = fmaxf(ax + bb.x, 0.f);
    float vy = fmaxf(ay + bb.y, 0.f);
    float2 w2a = ((const float2*)W2)[2 * lane];
    float2 w2b = ((const float2*)W2)[2 * lane + 1];
    float p0 = vx * w2a.x + vy * w2b.x;
    float p1 = vx * w2a.y + vy * w2b.y;
    #pragma unroll
    for (int off = 32; off; off >>= 1) {
        p0 += __shfl_xor(p0, off);
        p1 += __shfl_xor(p1, off);
    }
    if (lane == 0) ((float2*)h2)[i] = make_float2(p0, p1);
}

// ---- layer-2 aggregate + skip ----
__global__ __launch_bounds__(256) void agg2_kernel(const float* __restrict__ h2,
                                                   const float* __restrict__ dinv,
                                                   const int* __restrict__ row_ptr,
                                                   const int* __restrict__ col_src,
                                                   const float* __restrict__ skip,
                                                   float* __restrict__ out, int n) {
    int i = blockIdx.x * blockDim.x + threadIdx.x;
    if (i >= n) return;
    float di = dinv[i];
    const float2* h2v = (const float2*)h2;
    float2 self = h2v[i];
    float a0 = self.x * di * di, a1 = self.y * di * di;
    int beg = row_ptr[i], end = row_ptr[i + 1];
    for (int e = beg; e < end; ++e) {
        int s = col_src[e];
        float nrm = dinv[s] * di;
        float2 hs = h2v[s];
        a0 = fmaf(hs.x, nrm, a0);
        a1 = fmaf(hs.y, nrm, a1);
    }
    float2 sk = ((const float2*)skip)[i];
    ((float2*)out)[i] = make_float2(a0 + sk.x, a1 + sk.y);
}

extern "C" void kernel_launch(void* const* d_in, const int* in_sizes, int n_in,
                              void* d_out, int out_size, void* d_ws, size_t ws_size,
                              hipStream_t stream) {
    const float* x  = (const float*)d_in[0];
    const int*   ei = (const int*)d_in[1];
    const float* W1 = (const float*)d_in[2];
    const float* b1 = (const float*)d_in[3];
    const float* W2 = (const float*)d_in[4];
    const float* b2 = (const float*)d_in[5];
    const float* Ws = (const float*)d_in[6];
    const float* bs = (const float*)d_in[7];
    float* out = (float*)d_out;

    const int n = in_sizes[0] / IND;        // 100000
    const int E = in_sizes[1] / 2;          // 1600000
    const int NB = (n + 255) >> 8;          // 391 buckets

    char* ws = (char*)d_ws;
    size_t off = 0;
    auto alloc = [&](size_t bytes) { void* p = ws + off; off += (bytes + 255) & ~(size_t)255; return p; };
    int*            flag        = (int*)alloc(256);
    int*            bucket_len  = (int*)alloc((size_t)(MAXNB + 1) * 4);
    int*            bucket_base = (int*)alloc((size_t)(MAXNB + 1) * 4);
    unsigned*       slab        = (unsigned*)alloc((size_t)NB * SLAB * 4);
    int*            row_ptr     = (int*)alloc((size_t)(n + 1) * 4);
    float*          dinv        = (float*)alloc((size_t)n * 4);
    int*            col_src     = (int*)alloc((size_t)E * 4);
    unsigned short* hb          = (unsigned short*)alloc((size_t)n * HID * 2);
    float*          h2          = (float*)alloc((size_t)n * 2 * 4);
    float*          skip        = (float*)alloc((size_t)n * 2 * 4);
    unsigned short* w1t         = (unsigned short*)alloc((size_t)HID * KP * 2);
    (void)ws_size;

    hipMemsetAsync(bucket_len, 0, (size_t)NB * 4, stream);
    detect_kernel<<<1, 256, 0, stream>>>(ei, flag);
    w1t_kernel<<<(HID * KP + 255) / 256, 256, 0, stream>>>(W1, w1t);
    partition_kernel<<<(E + 8191) / 8192, 256, 0, stream>>>(ei, flag, bucket_len, slab, E, NB);
    bscan_kernel<<<1, 256, 0, stream>>>(bucket_len, bucket_base, row_ptr, n, NB);
    buildb_kernel<<<NB, 256, 0, stream>>>(slab, bucket_len, bucket_base, row_ptr, dinv, col_src, n);

    gemm1_kernel<<<(n + BM - 1) / BM, 256, 0, stream>>>(x, w1t, Ws, bs, b2, hb, skip, n);
    agg1_kernel<<<(n + 3) / 4, 256, 0, stream>>>((const unsigned*)hb, dinv, row_ptr, col_src, b1, W2, h2, n);
    agg2_kernel<<<(n + 255) / 256, 256, 0, stream>>>(h2, dinv, row_ptr, col_src, skip, out, n);
}

// Round 7
// 181.749 us; speedup vs baseline: 1.4125x; 1.0729x over previous
//
#include <hip/hip_runtime.h>
#include <hip/hip_bf16.h>

// SkipGCN: out = gcn(relu(gcn(x,W1,b1)),W2,b2) + x@Ws + bs
// N=100000, E=1600000, in=165, hid=128, out=2, fp32 in/out.
//
// R7 changes vs R6 (agg1 80us, gather-byte-bound: 192MB FETCH @ 2.5TB/s):
//  - h stored as fp8 e4m3 (OCP): gather row 256B -> 128B. No per-row scale
//    (|h|max ~4.4 << 448). Dequant = one v_cvt_pk_f32_fp8 per edge per lane.
//  - agg1 edge loop unroll 4 -> 8.
//  - bscan folded into buildb (each block scans bucket lens in LDS).
//  - memset+detect+w1t merged into setup_kernel. Launches 10 -> 7.

#define IND 165
#define HID 128
#define KP 192          // padded K for MFMA
#define BM 32           // rows per block (gemm1)
#define XSS2 208        // LDS row stride in bf16 (416B = 16B-aligned rows)
#define SLAB 8192
#define MAXNB 512

typedef __attribute__((ext_vector_type(8))) short short8v;
typedef __attribute__((ext_vector_type(4))) float float4v;
typedef __attribute__((ext_vector_type(2))) float float2v;

__device__ __forceinline__ unsigned short f2bf(float f) {
    unsigned u = __float_as_uint(f);
    unsigned r = (u + 0x7FFF + ((u >> 16) & 1)) >> 16;  // RNE
    return (unsigned short)r;
}
__device__ __forceinline__ float bf2f(unsigned short s) { return __uint_as_float(((unsigned)s) << 16); }

// ---- setup: w1t convert (blocks 0..95) + detect + zero bucket_len (block 96) ----
__global__ __launch_bounds__(256) void setup_kernel(const float* __restrict__ W1,
                                                    unsigned short* __restrict__ w1t,
                                                    const int* __restrict__ e32,
                                                    int* __restrict__ flag,
                                                    int* __restrict__ bucket_len, int NB) {
    int b = blockIdx.x;
    if (b < 96) {
        int t = b * 256 + threadIdx.x;          // t < 24576 = HID*KP
        int nn = t / KP, k = t - nn * KP;
        w1t[t] = (k < IND) ? f2bf(W1[k * HID + nn]) : (unsigned short)0;
    } else {
        __shared__ int nz;
        if (threadIdx.x == 0) nz = 0;
        __syncthreads();
        if (e32[2 * threadIdx.x + 1] != 0) atomicOr(&nz, 1);
        __syncthreads();
        if (threadIdx.x == 0) flag[0] = (nz == 0) ? 1 : 0;  // 1 => int64 layout
        for (int t = threadIdx.x; t < NB; t += 256) bucket_len[t] = 0;
    }
}

// ---- partition: edges -> per-bucket slabs of records (dstLow<<24 | src) ----
__global__ __launch_bounds__(256) void partition_kernel(const int* __restrict__ e32,
                                                        const int* __restrict__ flag,
                                                        int* __restrict__ bucket_len,
                                                        unsigned* __restrict__ slab,
                                                        int E, int NB) {
    __shared__ unsigned hist[MAXNB];
    __shared__ unsigned runbase[MAXNB];
    __shared__ unsigned cnt2[MAXNB];
    for (int t = threadIdx.x; t < NB; t += 256) { hist[t] = 0; cnt2[t] = 0; }
    __syncthreads();
    const int f = flag[0];
    const int base = blockIdx.x * 8192;
    unsigned rec[32];
    unsigned bk[32];
    #pragma unroll
    for (int j = 0; j < 32; ++j) {
        int e = base + j * 256 + threadIdx.x;
        if (e < E) {
            int src, dst;
            if (f) {
                int2 s2 = ((const int2*)e32)[e];
                int2 d2 = ((const int2*)e32)[E + e];
                src = s2.x; dst = d2.x;
            } else {
                src = e32[e];
                dst = e32[E + e];
            }
            unsigned b = (unsigned)dst >> 8;
            rec[j] = ((unsigned)(dst & 255) << 24) | (unsigned)src;
            bk[j] = b;
            atomicAdd(&hist[b], 1u);
        } else {
            bk[j] = 0xFFFFFFFFu;
            rec[j] = 0;
        }
    }
    __syncthreads();
    for (int t = threadIdx.x; t < NB; t += 256) {
        unsigned h = hist[t];
        runbase[t] = h ? (unsigned)atomicAdd(&bucket_len[t], (int)h) : 0u;
    }
    __syncthreads();
    #pragma unroll
    for (int j = 0; j < 32; ++j) {
        unsigned b = bk[j];
        if (b != 0xFFFFFFFFu) {
            unsigned p = runbase[b] + atomicAdd(&cnt2[b], 1u);
            if (p < SLAB) slab[(size_t)b * SLAB + p] = rec[j];
        }
    }
}

// ---- buildB: block per bucket; inline bucket-scan -> deg/dinv/row_ptr + col_src ----
__global__ __launch_bounds__(256) void buildb_kernel(const unsigned* __restrict__ slab,
                                                     const int* __restrict__ bucket_len,
                                                     int* __restrict__ row_ptr,
                                                     float* __restrict__ dinv,
                                                     int* __restrict__ col_src, int n, int NB) {
    __shared__ int qa[MAXNB], qb[MAXNB];
    const int b = blockIdx.x;
    const int t = threadIdx.x;
    // scan all bucket lengths to get this bucket's base
    for (int i = t; i < MAXNB; i += 256) qa[i] = (i < NB) ? min(bucket_len[i], SLAB) : 0;
    __syncthreads();
    int* s = qa; int* d = qb;
    for (int off = 1; off < MAXNB; off <<= 1) {
        for (int i = t; i < MAXNB; i += 256) d[i] = s[i] + ((i >= off) ? s[i - off] : 0);
        __syncthreads();
        int* tmp = s; s = d; d = tmp;
    }
    const int bb = (b == 0) ? 0 : s[b - 1];
    if (b == NB - 1 && t == 0) row_ptr[n] = s[NB - 1];
    const int len = min(bucket_len[b], SLAB);
    const unsigned* recs = slab + (size_t)b * SLAB;
    const int d0 = b << 8;
    __syncthreads();
    // per-node degree histogram + scan (reuse qa/qb first 256)
    __shared__ unsigned deg[256];
    __shared__ unsigned cur[256];
    deg[t] = 0;
    __syncthreads();
    for (int i = t; i < len; i += 256) atomicAdd(&deg[recs[i] >> 24], 1u);
    __syncthreads();
    unsigned dv = deg[t];
    qa[t] = (int)dv;
    __syncthreads();
    s = qa; d = qb;
    for (int off = 1; off < 256; off <<= 1) {
        d[t] = s[t] + ((t >= off) ? s[t - off] : 0);
        __syncthreads();
        int* tmp = s; s = d; d = tmp;
    }
    unsigned excl = (unsigned)s[t] - dv;
    if (d0 + t < n) {
        dinv[d0 + t] = rsqrtf(1.0f + (float)dv);
        row_ptr[d0 + t] = bb + (int)excl;
    }
    cur[t] = excl;
    __syncthreads();
    for (int i = t; i < len; i += 256) {
        unsigned r = recs[i];
        unsigned p = (unsigned)bb + atomicAdd(&cur[r >> 24], 1u);
        col_src[p] = (int)(r & 0xFFFFFFu);
    }
}

// ---- MFMA gemm1: hb8(fp8 e4m3) = x @ W1, fused skip = x @ Ws + bs + b2 ----
// BM=32 rows x 128 cols per block, 4 waves; wave w owns cols [32w,32w+32).
__global__ __launch_bounds__(256, 4) void gemm1_kernel(const float* __restrict__ x,
                                                       const unsigned short* __restrict__ w1t,
                                                       const float* __restrict__ Ws,
                                                       const float* __restrict__ bs,
                                                       const float* __restrict__ b2,
                                                       unsigned char* __restrict__ hb8,
                                                       float* __restrict__ skip, int n) {
    __shared__ unsigned short xs[BM * XSS2];
    const int row0 = blockIdx.x * BM;
    const int tid = threadIdx.x;
    const int wave = tid >> 6, lane = tid & 63;
    const int l15 = lane & 15, lk = (lane >> 4) * 8;

    // hoist B fragments (issued before staging; latency overlaps the copy)
    short8v bfr[12];
    #pragma unroll
    for (int nt2 = 0; nt2 < 2; ++nt2)
        #pragma unroll
        for (int ks = 0; ks < 6; ++ks)
            bfr[nt2 * 6 + ks] =
                *(const short8v*)(w1t + (size_t)((2 * wave + nt2) * 16 + l15) * KP + ks * 32 + lk);

    for (int t = tid; t < BM * (XSS2 - IND); t += 256) {
        int r = t / (XSS2 - IND), k = IND + (t - r * (XSS2 - IND));
        xs[r * XSS2 + k] = 0;
    }
    {
        const int rows = min(BM, n - row0);
        const int nflt = rows * IND;
        const float2* xsrc = (const float2*)(x + (size_t)row0 * IND);
        const int nf2 = nflt >> 1;
        for (int f = tid; f < nf2; f += 256) {
            float2 v = xsrc[f];
            int e0 = 2 * f;
            int r0 = e0 / IND, k0 = e0 - r0 * IND;
            xs[r0 * XSS2 + k0] = f2bf(v.x);
            int r1 = (k0 == IND - 1) ? r0 + 1 : r0;
            int k1 = (k0 == IND - 1) ? 0 : k0 + 1;
            xs[r1 * XSS2 + k1] = f2bf(v.y);
        }
        if ((nflt & 1) && tid == 0) {
            int e = nflt - 1;
            int r = e / IND, k = e - r * IND;
            xs[r * XSS2 + k] = f2bf(x[(size_t)row0 * IND + e]);
        }
    }
    __syncthreads();

    float4v acc[2][2];
    #pragma unroll
    for (int m = 0; m < 2; ++m)
        #pragma unroll
        for (int nt2 = 0; nt2 < 2; ++nt2) acc[m][nt2] = (float4v){0.f, 0.f, 0.f, 0.f};
    #pragma unroll
    for (int m = 0; m < 2; ++m) {
        const unsigned short* arow = xs + (m * 16 + l15) * XSS2;
        #pragma unroll
        for (int ks = 0; ks < 6; ++ks) {
            short8v a = *(const short8v*)(arow + ks * 32 + lk);
            acc[m][0] = __builtin_amdgcn_mfma_f32_16x16x32_bf16(a, bfr[ks], acc[m][0], 0, 0, 0);
            acc[m][1] = __builtin_amdgcn_mfma_f32_16x16x32_bf16(a, bfr[6 + ks], acc[m][1], 0, 0, 0);
        }
    }

    // epilogue: quantize f32 -> e4m3 byte; C layout col=lane&15, row=(lane>>4)*4+r
    #pragma unroll
    for (int m = 0; m < 2; ++m) {
        int orow0 = row0 + m * 16 + (lane >> 4) * 4;
        #pragma unroll
        for (int nt2 = 0; nt2 < 2; ++nt2) {
            int col = (2 * wave + nt2) * 16 + l15;
            #pragma unroll
            for (int r = 0; r < 4; ++r) {
                int row = orow0 + r;
                int pk = __builtin_amdgcn_cvt_pk_fp8_f32(acc[m][nt2][r], 0.f, 0, false);
                if (row < n) hb8[(size_t)row * HID + col] = (unsigned char)(pk & 0xFF);
            }
        }
    }

    // skip from LDS bf16: 8 threads per row
    {
        int r = tid >> 3, j = tid & 7;
        int row = row0 + r;
        float s0 = 0.f, s1 = 0.f;
        if (row < n) {
            const float2* Wsv = (const float2*)Ws;
            const unsigned short* xr = xs + r * XSS2;
            for (int k = j; k < IND; k += 8) {
                float xv = bf2f(xr[k]);
                float2 w = Wsv[k];
                s0 = fmaf(xv, w.x, s0);
                s1 = fmaf(xv, w.y, s1);
            }
        }
        s0 += __shfl_xor(s0, 1); s0 += __shfl_xor(s0, 2); s0 += __shfl_xor(s0, 4);
        s1 += __shfl_xor(s1, 1); s1 += __shfl_xor(s1, 2); s1 += __shfl_xor(s1, 4);
        if (j == 0 && row < n)
            ((float2*)skip)[row] = make_float2(s0 + bs[0] + b2[0], s1 + bs[1] + b2[1]);
    }
}

// ---- layer-1 aggregate (fp8 h) + relu + fused h2 = relu(agg+b1) @ W2 ----
// one wave per node; lane l owns channels {2l,2l+1} = one u16 of 2 fp8
__global__ __launch_bounds__(256) void agg1_kernel(const unsigned short* __restrict__ hb8,
                                                   const float* __restrict__ dinv,
                                                   const int* __restrict__ row_ptr,
                                                   const int* __restrict__ col_src,
                                                   const float* __restrict__ b1,
                                                   const float* __restrict__ W2,
                                                   float* __restrict__ h2, int n) {
    int wid = threadIdx.x >> 6, lane = threadIdx.x & 63;
    int i = blockIdx.x * 4 + wid;
    if (i >= n) return;
    float di = dinv[i];
    float ax, ay;
    {
        unsigned v = hb8[(size_t)i * 64 + lane];
        float2v f = __builtin_amdgcn_cvt_pk_f32_fp8((int)v, false);
        float w = di * di;
        ax = f.x * w;
        ay = f.y * w;
    }
    int e = row_ptr[i], end = row_ptr[i + 1];
    for (; e + 8 <= end; e += 8) {
        int   sv[8];
        float nv[8];
        unsigned uv[8];
        #pragma unroll
        for (int j = 0; j < 8; ++j) sv[j] = col_src[e + j];
        #pragma unroll
        for (int j = 0; j < 8; ++j) nv[j] = dinv[sv[j]] * di;
        #pragma unroll
        for (int j = 0; j < 8; ++j) uv[j] = hb8[(size_t)sv[j] * 64 + lane];
        #pragma unroll
        for (int j = 0; j < 8; ++j) {
            float2v f = __builtin_amdgcn_cvt_pk_f32_fp8((int)uv[j], false);
            ax = fmaf(f.x, nv[j], ax);
            ay = fmaf(f.y, nv[j], ay);
        }
    }
    for (; e < end; ++e) {
        int s = col_src[e];
        float nrm = dinv[s] * di;
        unsigned v = hb8[(size_t)s * 64 + lane];
        float2v f = __builtin_amdgcn_cvt_pk_f32_fp8((int)v, false);
        ax = fmaf(f.x, nrm, ax);
        ay = fmaf(f.y, nrm, ay);
    }
    float2 bb = ((const float2*)b1)[lane];
    float vx = fmaxf(ax + bb.x, 0.f);
    float vy = fmaxf(ay + bb.y, 0.f);
    float2 w2a = ((const float2*)W2)[2 * lane];
    float2 w2b = ((const float2*)W2)[2 * lane + 1];
    float p0 = vx * w2a.x + vy * w2b.x;
    float p1 = vx * w2a.y + vy * w2b.y;
    #pragma unroll
    for (int off = 32; off; off >>= 1) {
        p0 += __shfl_xor(p0, off);
        p1 += __shfl_xor(p1, off);
    }
    if (lane == 0) ((float2*)h2)[i] = make_float2(p0, p1);
}

// ---- layer-2 aggregate + skip ----
__global__ __launch_bounds__(256) void agg2_kernel(const float* __restrict__ h2,
                                                   const float* __restrict__ dinv,
                                                   const int* __restrict__ row_ptr,
                                                   const int* __restrict__ col_src,
                                                   const float* __restrict__ skip,
                                                   float* __restrict__ out, int n) {
    int i = blockIdx.x * blockDim.x + threadIdx.x;
    if (i >= n) return;
    float di = dinv[i];
    const float2* h2v = (const float2*)h2;
    float2 self = h2v[i];
    float a0 = self.x * di * di, a1 = self.y * di * di;
    int beg = row_ptr[i], end = row_ptr[i + 1];
    for (int e = beg; e < end; ++e) {
        int s = col_src[e];
        float nrm = dinv[s] * di;
        float2 hs = h2v[s];
        a0 = fmaf(hs.x, nrm, a0);
        a1 = fmaf(hs.y, nrm, a1);
    }
    float2 sk = ((const float2*)skip)[i];
    ((float2*)out)[i] = make_float2(a0 + sk.x, a1 + sk.y);
}

extern "C" void kernel_launch(void* const* d_in, const int* in_sizes, int n_in,
                              void* d_out, int out_size, void* d_ws, size_t ws_size,
                              hipStream_t stream) {
    const float* x  = (const float*)d_in[0];
    const int*   ei = (const int*)d_in[1];
    const float* W1 = (const float*)d_in[2];
    const float* b1 = (const float*)d_in[3];
    const float* W2 = (const float*)d_in[4];
    const float* b2 = (const float*)d_in[5];
    const float* Ws = (const float*)d_in[6];
    const float* bs = (const float*)d_in[7];
    float* out = (float*)d_out;

    const int n = in_sizes[0] / IND;        // 100000
    const int E = in_sizes[1] / 2;          // 1600000
    const int NB = (n + 255) >> 8;          // 391 buckets

    char* ws = (char*)d_ws;
    size_t off = 0;
    auto alloc = [&](size_t bytes) { void* p = ws + off; off += (bytes + 255) & ~(size_t)255; return p; };
    int*            flag        = (int*)alloc(256);
    int*            bucket_len  = (int*)alloc((size_t)(MAXNB + 1) * 4);
    unsigned*       slab        = (unsigned*)alloc((size_t)NB * SLAB * 4);
    int*            row_ptr     = (int*)alloc((size_t)(n + 1) * 4);
    float*          dinv        = (float*)alloc((size_t)n * 4);
    int*            col_src     = (int*)alloc((size_t)E * 4);
    unsigned char*  hb8         = (unsigned char*)alloc((size_t)n * HID);
    float*          h2          = (float*)alloc((size_t)n * 2 * 4);
    float*          skip        = (float*)alloc((size_t)n * 2 * 4);
    unsigned short* w1t         = (unsigned short*)alloc((size_t)HID * KP * 2);
    (void)ws_size;

    setup_kernel<<<97, 256, 0, stream>>>(W1, w1t, ei, flag, bucket_len, NB);
    partition_kernel<<<(E + 8191) / 8192, 256, 0, stream>>>(ei, flag, bucket_len, slab, E, NB);
    buildb_kernel<<<NB, 256, 0, stream>>>(slab, bucket_len, row_ptr, dinv, col_src, n, NB);

    gemm1_kernel<<<(n + BM - 1) / BM, 256, 0, stream>>>(x, w1t, Ws, bs, b2, hb8, skip, n);
    agg1_kernel<<<(n + 3) / 4, 256, 0, stream>>>((const unsigned short*)hb8, dinv, row_ptr, col_src, b1, W2, h2, n);
    agg2_kernel<<<(n + 255) / 256, 256, 0, stream>>>(h2, dinv, row_ptr, col_src, skip, out, n);
}